// Round 2
// baseline (262.154 us; speedup 1.0000x reference)
//
#include <hip/hip_runtime.h>
#include <hip/hip_bf16.h>

// GraphConvolution: out = relu( (W@x + b) @ adj^T + x ), B=4096, C=256, N=25.
// Aggregate-first: y[c,m] = sum_n x[c,n]*adj[m,n]  (MFMA, A=adj bf16, B=x bf16)
//                  out[o,m] = sum_c W[o,c]*y[c,m] + b_o*rowsum(adj)[m] + x[o,m]
// Both matmuls on mfma_f32_16x16x32_bf16. One block per b, 256 threads.
// LDS: xbf[256][40] bf16 (20480 B) aliased by ys[32][264] (16896 B) across a
// barrier + adjbf[32][40] (2560 B) + adjS/biasS -> 24.2 KB => 6 blocks/CU.

#define BATCH 4096
#define C 256
#define N 25
#define XS 40    // xbf/adjbf row stride in bf16 (80 B, 16B-aligned rows)
#define YS 264   // ys row stride in bf16 (528 B, 16B-aligned rows)

typedef __bf16 bf16x8 __attribute__((ext_vector_type(8)));
typedef float f32x4 __attribute__((ext_vector_type(4)));

// fp32 W -> bf16 W in workspace (128 KiB of d_ws)
__global__ void cvt_w_kernel(const float* __restrict__ W, __bf16* __restrict__ Wb) {
    int i = blockIdx.x * 256 + threadIdx.x;
    Wb[i] = (__bf16)W[i];
}

__global__ __launch_bounds__(256) void gcn_fused_kernel(
    const float* __restrict__ x, const float* __restrict__ adj,
    const float* __restrict__ bias, const __bf16* __restrict__ Wb,
    float* __restrict__ out)
{
    __shared__ __align__(16) unsigned char smem_u[C * XS * 2]; // xbf, later ys
    __shared__ __align__(16) __bf16 adjbf[32 * XS];
    __shared__ float adjS[32];
    __shared__ float biasS[C];

    __bf16* xbf = (__bf16*)smem_u;  // [C][XS], n=25..31 zeroed
    __bf16* ys  = (__bf16*)smem_u;  // [32][YS], aliases xbf after barrier 2

    const int tid = threadIdx.x;
    const int b = blockIdx.x;
    const float* xb = x + (size_t)b * (C * N);

    // ---- stage x -> bf16 LDS (coalesced float4, scattered b16 writes) ----
    {
        const float4* xb4 = (const float4*)xb;
        for (int i = tid; i < (C * N) / 4; i += 256) {
            float4 v = xb4[i];
            int e = i * 4;
            int c = e / N, n = e - c * N;
            float f[4] = {v.x, v.y, v.z, v.w};
            #pragma unroll
            for (int q = 0; q < 4; ++q) {
                xbf[c * XS + n] = (__bf16)f[q];
                ++n; if (n == N) { n = 0; ++c; }
            }
        }
    }
    // zero K-pad n=25..31 of own row (disjoint from value writes: no race)
    #pragma unroll
    for (int n = N; n < 32; ++n) xbf[tid * XS + n] = (__bf16)0.f;

    // ---- stage adj -> bf16 LDS + row sums; zero pads (disjoint addrs) ----
    for (int e = tid; e < N * N; e += 256) {
        int m = e / N, n = e - m * N;
        adjbf[m * XS + n] = (__bf16)adj[e];
    }
    if (tid < N) {
        #pragma unroll
        for (int n = N; n < 32; ++n) adjbf[tid * XS + n] = (__bf16)0.f;
        float s = 0.f;
        for (int n = 0; n < N; ++n) s += adj[tid * N + n];
        adjS[tid] = s;
    } else if (tid < 32) {
        #pragma unroll
        for (int n = 0; n < 32; ++n) adjbf[tid * XS + n] = (__bf16)0.f;
        adjS[tid] = 0.f;
    }
    biasS[tid] = bias[tid];
    __syncthreads();

    const int wv = tid >> 6, lane = tid & 63;
    const int quad = lane >> 4, l15 = lane & 15;

    // ---- aggregation MFMA: D[m][c] = sum_n adj[m][n] * x[c][n] ----
    // wave wv owns c-tiles ctl=0..3 at c0 = wv*64 + ctl*16; m-tiles mt=0,1.
    f32x4 yacc[4][2];
    {
        bf16x8 a0 = *(const bf16x8*)&adjbf[l15 * XS + quad * 8];         // A[m=l15][n]
        bf16x8 a1 = *(const bf16x8*)&adjbf[(16 + l15) * XS + quad * 8];  // rows 25..31 zeroed
        #pragma unroll
        for (int ctl = 0; ctl < 4; ++ctl) {
            int c = wv * 64 + ctl * 16 + l15;
            bf16x8 xf = *(const bf16x8*)&xbf[c * XS + quad * 8];         // B[n][c]
            yacc[ctl][0] = __builtin_amdgcn_mfma_f32_16x16x32_bf16(a0, xf, (f32x4)0.f, 0, 0, 0);
            yacc[ctl][1] = __builtin_amdgcn_mfma_f32_16x16x32_bf16(a1, xf, (f32x4)0.f, 0, 0, 0);
        }
    }
    __syncthreads();  // all xbf reads complete -> safe to overwrite with ys

    // ---- y (C-layout: col c=l15-ish, row m=quad*4+r) -> bf16 ys[m][c] ----
    #pragma unroll
    for (int ctl = 0; ctl < 4; ++ctl) {
        int c = wv * 64 + ctl * 16 + l15;
        #pragma unroll
        for (int mt = 0; mt < 2; ++mt)
            #pragma unroll
            for (int r = 0; r < 4; ++r) {
                int m = mt * 16 + quad * 4 + r;
                ys[m * YS + c] = (__bf16)yacc[ctl][mt][r];
            }
    }
    __syncthreads();

    // ---- main GEMM: out[o][m] = sum_c W[o][c] * y[c][m] ----
    const int o0 = wv * 64;
    f32x4 acc[4][2];
    #pragma unroll
    for (int ot = 0; ot < 4; ++ot)
        #pragma unroll
        for (int mt = 0; mt < 2; ++mt) acc[ot][mt] = (f32x4)0.f;

    #pragma unroll 2
    for (int kk = 0; kk < 8; ++kk) {
        const int k = kk * 32 + quad * 8;
        bf16x8 bf[2];
        #pragma unroll
        for (int mt = 0; mt < 2; ++mt)
            bf[mt] = *(const bf16x8*)&ys[(mt * 16 + l15) * YS + k];      // B[c][m]
        #pragma unroll
        for (int ot = 0; ot < 4; ++ot) {
            bf16x8 af = *(const bf16x8*)&Wb[(size_t)(o0 + ot * 16 + l15) * C + k]; // A[o][c], L2-hot
            #pragma unroll
            for (int mt = 0; mt < 2; ++mt)
                acc[ot][mt] = __builtin_amdgcn_mfma_f32_16x16x32_bf16(af, bf[mt], acc[ot][mt], 0, 0, 0);
        }
    }

    // ---- epilogue: + bias[o]*rowsum(adj)[m] + x[o][m], relu ----
    // residual x re-read from global (L2/L3-hot; avoids 25.6 KB fp32 LDS copy)
    float* outb = out + (size_t)b * (C * N);
    #pragma unroll
    for (int ot = 0; ot < 4; ++ot) {
        #pragma unroll
        for (int mt = 0; mt < 2; ++mt) {
            const int m = mt * 16 + l15;
            if (m < N) {
                #pragma unroll
                for (int r = 0; r < 4; ++r) {
                    const int o = o0 + ot * 16 + quad * 4 + r;
                    float v = acc[ot][mt][r] + biasS[o] * adjS[m] + xb[o * N + m];
                    outb[o * N + m] = v > 0.f ? v : 0.f;
                }
            }
        }
    }
}

extern "C" void kernel_launch(void* const* d_in, const int* in_sizes, int n_in,
                              void* d_out, int out_size, void* d_ws, size_t ws_size,
                              hipStream_t stream) {
    (void)in_sizes; (void)n_in; (void)out_size; (void)ws_size;
    const float* x    = (const float*)d_in[0];   // [4096, 256, 25]
    const float* adj  = (const float*)d_in[1];   // [25, 25]
    const float* W    = (const float*)d_in[2];   // [256, 256]
    const float* bias = (const float*)d_in[3];   // [256]
    float* out = (float*)d_out;
    __bf16* Wb = (__bf16*)d_ws;                  // 128 KiB bf16 W

    cvt_w_kernel<<<(C * C) / 256, 256, 0, stream>>>(W, Wb);
    gcn_fused_kernel<<<BATCH, 256, 0, stream>>>(x, adj, bias, Wb, out);
}